// Round 10
// baseline (106.255 us; speedup 1.0000x reference)
//
#include <hip/hip_runtime.h>
#include <math.h>

// Problem constants
#define BB   4
#define CC   128
#define HH   64
#define WW   64
#define OUTC 128
#define KK   25     // 5x5 attention taps
#define PXB  16     // pixels per block (quarter row)
#define SJ   20     // staged cols: 16 + 4 halo

typedef __attribute__((ext_vector_type(8))) short short8;   // 8 bf16
typedef __attribute__((ext_vector_type(4))) float floatx4;  // MFMA acc

__device__ __forceinline__ unsigned short f32_to_bf16(float v) {
    unsigned int u = __float_as_uint(v);
    u += 0x7fffu + ((u >> 16) & 1u);          // RNE
    return (unsigned short)(u >> 16);
}
__device__ __forceinline__ float bf16_to_f32(unsigned short h) {
    return __uint_as_float(((unsigned int)h) << 16);
}

// ---------------------------------------------------------------------------
// Kernel 0 (prep): identical to rounds 8/9 (verified).
//  i < 16384:  w2o[o][c] = bf16( sum_r w2[o, c*4+r] )   (o-major, MFMA A)
//  else:       w1f = conv1 weights pre-packed in MFMA A-fragment lane order,
//              bf16 hi/lo split:
//              w1f[((((wt*9+dydx)*2+mt)*4+ks)*64+lane)*8+i8]
// ---------------------------------------------------------------------------
__global__ void prep_kernel(const float* __restrict__ w2,
                            const float* __restrict__ w1,
                            unsigned short* __restrict__ w2o,
                            unsigned short* __restrict__ w1f) {
    int i = blockIdx.x * 256 + threadIdx.x;
    if (i < 16384) {
        int o = i >> 7, c = i & 127;
        const float* p = w2 + o * (4 * CC) + c * 4;
        w2o[o * CC + c] = f32_to_bf16(p[0] + p[1] + p[2] + p[3]);
    } else {
        int f = i - 16384;            // 0..73727
        int i8 = f & 7;  int rest = f >> 3;
        int lane = rest & 63; rest >>= 6;
        int ks = rest & 3;  rest >>= 2;
        int mt = rest & 1;  rest >>= 1;
        int dydx = rest % 9;
        int wt   = rest / 9;          // 0 = hi, 1 = lo
        int kk = mt * 16 + (lane & 15);
        int c  = ks * 32 + (lane >> 4) * 8 + i8;
        unsigned short o16 = 0;
        if (kk < KK) {
            float v = w1[(size_t)(kk * CC + c) * 9 + dydx];
            unsigned short hi = f32_to_bf16(v);
            o16 = wt ? f32_to_bf16(v - bf16_to_f32(hi)) : hi;
        }
        w1f[f] = o16;
    }
}

// ---------------------------------------------------------------------------
// Fused kernel: conv1-as-MFMA (K-split) + softmax + attention + MFMA + store.
// grid 1024 = (b, h, wq): 16-px quarter-row, 256 threads (4 waves).
//
// ROUND 8/9 LESSON: every round since r2 ran 2048 total waves = 8 waves/CU
// = 2/SIMD (block shape varied, occupancy didn't) and all landed at the
// same latency-exposed plateau. px-parallelism is exhausted, so this round
// K-SPLITS the conv across waves: wave (mt=wv&1, kh=wv>>1) computes
// D[16kk][16px] over c-half [64kh, 64kh+64) — 54 MFMA each — and merges
// partials via f32 atomicAdd into bias-initialized pk (exact same sum,
// reassociated). Grid 1024 x 4 waves = 4096 waves = 16 waves/CU (2x).
// LDS 32.4KB -> exactly 4 blocks/CU; __launch_bounds__(256,2) is the
// PROVEN no-spill config (r2/r4: VGPR=116 <= 128 = the 16-waves/CU HW
// threshold). NO forced caps (r3/r5/r6 spill lesson).
//
//  stage : xs_hi/xs_lo[row 0..2][j 0..19][c^swz] bf16 (r8/r9-proven),
//          wave wv stages c in [32wv,32wv+32); halo via clamp loop.
//  conv  : 9(dydx) x 2(ks of this kh) x 3 hi/lo terms = 54 MFMA/wave;
//          A coalesced from w1f (L2-hot), B from xs.
//  phase C / softmax / MFMA2 / epilogue: r2/r4-proven 256-thread layouts.
// ---------------------------------------------------------------------------
__global__ __launch_bounds__(256, 2) void fused_kernel(
        const float* __restrict__ x,
        const unsigned short* __restrict__ w1f,
        const unsigned short* __restrict__ w2o,
        const float* __restrict__ b1,
        const float* __restrict__ b2,
        float* __restrict__ out) {
    __shared__ unsigned short xs_hi[3 * SJ * 128];   // 15360 B
    __shared__ unsigned short xs_lo[3 * SJ * 128];   // 15360 B
    __shared__ float pk[KK * PXB];                   // logits (1.6 KB)
    unsigned short* sKT = xs_hi;     // 16 x 136 bf16 overlay (4.35 KB)

    // XCD swizzle (1024 % 8 == 0 -> bijective)
    int bid0 = blockIdx.x;
    int bid  = (bid0 & 7) * 128 + (bid0 >> 3);
    int wq = bid & 3;
    int h  = (bid >> 2) & 63;
    int b  = bid >> 8;
    int t  = threadIdx.x;
    int lane = t & 63;
    int wv = t >> 6;                 // 0..3

    const float* xb = x + (size_t)b * CC * (HH * WW);

    // ---- init logits with bias ----
    for (int i = t; i < KK * PXB; i += 256) pk[i] = b1[i >> 4];

    // ---- stage x rows h-1..h+1 transposed+swizzled, bf16 hi/lo ----
    {
        // main 16 cols: lane = (jj 0..15, cc 0..3); wave wv -> 32 c.
        int jj = lane & 15, cc = lane >> 4;
        int j  = jj + 2;
        int swz = (j & 15) << 3;
        for (int ci = 0; ci < 8; ++ci) {
            int c  = wv * 32 + ci * 4 + cc;
            int cs = c ^ swz;
            const float* xc = xb + (size_t)c * (HH * WW) + wq * 16 + jj;
            #pragma unroll
            for (int r = 0; r < 3; ++r) {
                int y = h - 1 + r;
                float v = (y >= 0 && y < HH) ? xc[y * WW] : 0.f;
                unsigned short hi = f32_to_bf16(v);
                unsigned short lo = f32_to_bf16(v - bf16_to_f32(hi));
                xs_hi[(r * SJ + j) * 128 + cs] = hi;
                xs_lo[(r * SJ + j) * 128 + cs] = lo;
            }
        }
        // halo cols j in {0,1,18,19} (xcol = 16wq + {-2,-1,16,17})
        for (int i = t; i < 3 * 4 * 128; i += 256) {
            int jh = i & 3;
            int c  = (i >> 2) & 127;
            int r  = i >> 9;
            int j2 = (jh < 2) ? jh : 16 + jh;
            int xcol = wq * 16 + j2 - 2;
            int y = h - 1 + r;
            float v = (xcol >= 0 && xcol < WW && y >= 0 && y < HH)
                    ? xb[(size_t)c * (HH * WW) + y * WW + xcol] : 0.f;
            unsigned short hi = f32_to_bf16(v);
            unsigned short lo = f32_to_bf16(v - bf16_to_f32(hi));
            int cs2 = c ^ ((j2 & 15) << 3);
            xs_hi[(r * SJ + j2) * 128 + cs2] = hi;
            xs_lo[(r * SJ + j2) * 128 + cs2] = lo;
        }
    }
    __syncthreads();

    // ---- conv1 via MFMA, K-split: wave (mt, kh) -> c-half kh ----
    int fpx = lane & 15, quad = lane >> 4;
    int mt = wv & 1, kh = wv >> 1;
    floatx4 acc = {0.f, 0.f, 0.f, 0.f};
    for (int dydx = 0; dydx < 9; ++dydx) {
        int r   = dydx / 3;
        int dxm = dydx - 3 * r;
        int j   = fpx + dxm + 1;                 // staged col, 1..18
        int rowbase = (r * SJ + j) * 128;
        int swz = (j & 15) << 3;
        const unsigned short* whb = w1f + (dydx * 2 + mt) * 2048 + lane * 8;
        #pragma unroll
        for (int kq = 0; kq < 2; ++kq) {
            int ks = kh * 2 + kq;
            int cb = (ks * 32 + quad * 8) ^ swz;
            short8 Ah = *(const short8*)(whb + ks * 512);
            short8 Al = *(const short8*)(whb + 36864 + ks * 512);
            short8 Bh = *(const short8*)&xs_hi[rowbase + cb];
            short8 Bl = *(const short8*)&xs_lo[rowbase + cb];
            acc = __builtin_amdgcn_mfma_f32_16x16x32_bf16(Ah, Bh, acc, 0, 0, 0);
            acc = __builtin_amdgcn_mfma_f32_16x16x32_bf16(Ah, Bl, acc, 0, 0, 0);
            acc = __builtin_amdgcn_mfma_f32_16x16x32_bf16(Al, Bh, acc, 0, 0, 0);
        }
    }
    #pragma unroll
    for (int reg = 0; reg < 4; ++reg) {          // D row = quad*4+reg
        int kk = mt * 16 + quad * 4 + reg;
        if (kk < KK) atomicAdd(&pk[kk * PXB + fpx], acc[reg]);
    }
    __syncthreads();   // pk ready; xs dead -> sKT region reusable

    // ---- phase C: in-register softmax + attention straight from L1/L2 ----
    // thread = (pp2 = t&7 -> px {2pp2, 2pp2+1}, cw = t>>3 -> 4 channels)
    int pp2 = t & 7, cw = t >> 3;

    float2 lg[KK];
    #pragma unroll
    for (int k = 0; k < KK; ++k) lg[k] = *(const float2*)&pk[k * PXB + 2 * pp2];
    float m0 = -1e30f, m1 = -1e30f;
    #pragma unroll
    for (int k = 0; k < KK; ++k) { m0 = fmaxf(m0, lg[k].x); m1 = fmaxf(m1, lg[k].y); }
    float s0 = 0.f, s1 = 0.f;
    #pragma unroll
    for (int k = 0; k < KK; ++k) {
        lg[k].x = __expf(lg[k].x - m0); s0 += lg[k].x;
        lg[k].y = __expf(lg[k].y - m1); s1 += lg[k].y;
    }
    float i0 = 1.f / s0, i1 = 1.f / s1;
    #pragma unroll
    for (int k = 0; k < KK; ++k) { lg[k].x *= i0; lg[k].y *= i1; }

    int colg = wq * 16 + 2 * pp2 - 2;
    int coff[3]; float cmask[3];
    #pragma unroll
    for (int jx = 0; jx < 3; ++jx) {
        int cg = colg + 2 * jx;
        cmask[jx] = (cg >= 0 && cg <= WW - 2) ? 1.f : 0.f;
        coff[jx]  = min(max(cg, 0), WW - 2);
    }
    int yoff[5]; float msk[15];
    #pragma unroll
    for (int di = 0; di < 5; ++di) {
        int y = h + di - 2;
        float rm = (y >= 0 && y < HH) ? 1.f : 0.f;
        yoff[di] = min(max(y, 0), HH - 1) * WW;
        #pragma unroll
        for (int jx = 0; jx < 3; ++jx) msk[di * 3 + jx] = rm * cmask[jx];
    }

    #pragma unroll 2
    for (int i4 = 0; i4 < 4; ++i4) {
        int c = i4 * 32 + cw;
        const float* xc = xb + (size_t)c * (HH * WW);
        float2 xv[15];
        #pragma unroll
        for (int di = 0; di < 5; ++di)
            #pragma unroll
            for (int jx = 0; jx < 3; ++jx) {
                float2 v = *(const float2*)(xc + yoff[di] + coff[jx]);
                float mm = msk[di * 3 + jx];
                xv[di * 3 + jx] = make_float2(v.x * mm, v.y * mm);
            }
        float t0 = 0.f, t1 = 0.f;
        #pragma unroll
        for (int di = 0; di < 5; ++di) {
            float2 x01 = xv[di * 3 + 0];
            float2 x23 = xv[di * 3 + 1];
            float2 x45 = xv[di * 3 + 2];
            t0 += lg[di*5+0].x * x01.x + lg[di*5+1].x * x01.y
                + lg[di*5+2].x * x23.x + lg[di*5+3].x * x23.y
                + lg[di*5+4].x * x45.x;
            t1 += lg[di*5+0].y * x01.y + lg[di*5+1].y * x23.x
                + lg[di*5+2].y * x23.y + lg[di*5+3].y * x45.x
                + lg[di*5+4].y * x45.y;
        }
        sKT[(2 * pp2) * 136 + c]     = f32_to_bf16(t0);
        sKT[(2 * pp2 + 1) * 136 + c] = f32_to_bf16(t1);
    }
    __syncthreads();

    // ---- MFMA2: C[o][px] = sum_c W2s[o][c] * s[c][px] ----
    // wave wv owns o-rows [32wv, 32wv+32): 2 o-tiles x 4 ks = 8 MFMA.
    floatx4 am[2] = {{0.f,0.f,0.f,0.f},{0.f,0.f,0.f,0.f}};
    #pragma unroll
    for (int ks = 0; ks < 4; ++ks) {
        short8 bf  = *(const short8*)&sKT[fpx * 136 + ks*32 + quad*8];
        short8 af0 = *(const short8*)&w2o[(size_t)(32*wv      + fpx) * CC + ks*32 + quad*8];
        short8 af1 = *(const short8*)&w2o[(size_t)(32*wv + 16 + fpx) * CC + ks*32 + quad*8];
        am[0] = __builtin_amdgcn_mfma_f32_16x16x32_bf16(af0, bf, am[0], 0, 0, 0);
        am[1] = __builtin_amdgcn_mfma_f32_16x16x32_bf16(af1, bf, am[1], 0, 0, 0);
    }

    // ---- epilogue: D[row=quad*4+reg][col=fpx] + b2, 2x2-replicated write ----
    float* ob = out + (size_t)b * OUTC * (4 * HH * WW);
    int y0 = 2 * h;
    int pxo = wq * 16 + fpx;
    #pragma unroll
    for (int mt2 = 0; mt2 < 2; ++mt2) {
        #pragma unroll
        for (int reg = 0; reg < 4; ++reg) {
            int o = 32*wv + 16*mt2 + quad*4 + reg;
            float v = am[mt2][reg] + b2[o];
            float2 v2 = make_float2(v, v);
            float* r0p = ob + ((size_t)o * (2*HH) + y0) * (2*WW) + 2*pxo;
            *(float2*)(r0p)        = v2;
            *(float2*)(r0p + 2*WW) = v2;
        }
    }
}

// ---------------------------------------------------------------------------
extern "C" void kernel_launch(void* const* d_in, const int* in_sizes, int n_in,
                              void* d_out, int out_size, void* d_ws, size_t ws_size,
                              hipStream_t stream) {
    const float* x  = (const float*)d_in[0];
    const float* w1 = (const float*)d_in[1];
    const float* b1 = (const float*)d_in[2];
    const float* w2 = (const float*)d_in[3];
    const float* b2 = (const float*)d_in[4];
    float* out = (float*)d_out;

    unsigned short* w2o = (unsigned short*)d_ws;               // 32 KB
    unsigned short* w1f = w2o + (size_t)OUTC * CC;             // 147.5 KB

    prep_kernel<<<(16384 + 73728) / 256, 256, 0, stream>>>(w2, w1, w2o, w1f);
    fused_kernel<<<BB * HH * 4, 256, 0, stream>>>(x, w1f, w2o, b1, b2, out);
}

// Round 12
// 94.944 us; speedup vs baseline: 1.1191x; 1.1191x over previous
//
#include <hip/hip_runtime.h>
#include <math.h>

// Problem constants
#define BB   4
#define CC   128
#define HH   64
#define WW   64
#define OUTC 128
#define KK   25     // 5x5 attention taps
#define PXB  16     // pixels per block (quarter row)
#define SJ   20     // staged cols: 16 + 4 halo

typedef __attribute__((ext_vector_type(8))) short short8;   // 8 bf16
typedef _Float16 half8  __attribute__((ext_vector_type(8)));
typedef __fp16   fp16x2 __attribute__((ext_vector_type(2))); // cvt_pkrtz ret
typedef __attribute__((ext_vector_type(4))) float floatx4;  // MFMA acc

__device__ __forceinline__ unsigned short f32_to_bf16(float v) {
    unsigned int u = __float_as_uint(v);
    u += 0x7fffu + ((u >> 16) & 1u);          // RNE
    return (unsigned short)(u >> 16);
}

// ---------------------------------------------------------------------------
// Kernel 0 (prep):
//  i < 16384:        w2o[o][c] = bf16( sum_r w2[o, c*4+r] )  (o-major, MFMA A)
//  16384..+36864:    w1f = conv1 weights as SINGLE fp16 in MFMA A-fragment
//                    lane order: w1f[(((dydx*2+mt)*4+ks)*64+lane)*8+i8]
//                     = f16( w1[kk=mt*16+(lane&15)][c=ks*32+(lane>>4)*8+i8]
//                            [dy=dydx/3][dx=dydx%3] ), 0 for kk>=25.
//  fp16 single-term replaces r8/r9's bf16 hi/lo: per-term rel err ~2^-10 ->
//  logit abs err ~0.002, negligible vs the 0.0156 absmax of the bf16 MFMA2.
// ---------------------------------------------------------------------------
__global__ void prep_kernel(const float* __restrict__ w2,
                            const float* __restrict__ w1,
                            unsigned short* __restrict__ w2o,
                            unsigned short* __restrict__ w1f) {
    int i = blockIdx.x * 256 + threadIdx.x;
    if (i < 16384) {
        int o = i >> 7, c = i & 127;
        const float* p = w2 + o * (4 * CC) + c * 4;
        w2o[o * CC + c] = f32_to_bf16(p[0] + p[1] + p[2] + p[3]);
    } else if (i < 16384 + 36864) {
        int f = i - 16384;            // 0..36863
        int i8   = f & 7;
        int lane = (f >> 3) & 63;
        int ks   = (f >> 9) & 3;
        int mt   = (f >> 11) & 1;
        int dydx = f >> 12;           // 0..8
        int kk = mt * 16 + (lane & 15);
        int c  = ks * 32 + (lane >> 4) * 8 + i8;
        float v = (kk < KK) ? w1[(size_t)(kk * CC + c) * 9 + dydx] : 0.f;
        _Float16 hv = (_Float16)v;    // RNE
        w1f[f] = *(unsigned short*)&hv;
    }
}

// ---------------------------------------------------------------------------
// Fused kernel: conv1-as-MFMA(fp16) + softmax + attention + MFMA + 2x2 store.
// grid 1024 = (b, h, wq): 16-px quarter-row, 128 threads (2 waves) — the r9
// geometry (best fused so far; r10's K-split/atomics regressed it, reverted).
//
// THIS ROUND'S LEVERS (occupancy pushes are exhausted — r3/5/6/9/10):
//  1. fp16 single-term conv: MFMA 108->36, A/B traffic halved, xs halved.
//  2. cvt_pkrtz staging: 1 instr packs 2 f32->2 f16, 1 u32 LDS store per
//     c-pair (r9's bf16 hi/lo split cost ~8 VALU/value = ~380/thread).
//  3. phase C 2-stage pipeline (T14): chunk i+1's 15 float2 loads issued
//     BEFORE chunk i's FMAs -> 8 exposed ~300cy L2 windows -> ~2.
//  4. conv dydx loop fully unrolled: all 36 A-loads + 36 ds_reads visible
//     to the scheduler for deep vmcnt/lgkmcnt pipelining.
// LDS: xs 15KB(f16) + pk 1.6KB = 17KB; sKT overlays xs after conv.
// __launch_bounds__(128,2): 256-reg budget, proven no-spill.
// ---------------------------------------------------------------------------
__global__ __launch_bounds__(128, 2) void fused_kernel(
        const float* __restrict__ x,
        const unsigned short* __restrict__ w1f,
        const unsigned short* __restrict__ w2o,
        const float* __restrict__ b1,
        const float* __restrict__ b2,
        float* __restrict__ out) {
    __shared__ _Float16 xs[3 * SJ * 128];            // 15360 B
    __shared__ float pk[KK * PXB];                   // 1600 B
    unsigned short* sKT = (unsigned short*)xs;       // 16x136 bf16 overlay

    // XCD swizzle (1024 % 8 == 0 -> bijective)
    int bid0 = blockIdx.x;
    int bid  = (bid0 & 7) * 128 + (bid0 >> 3);
    int wq = bid & 3;
    int h  = (bid >> 2) & 63;
    int b  = bid >> 8;
    int t  = threadIdx.x;
    int lane = t & 63;
    int wv = t >> 6;                 // 0..1

    const float* xb = x + (size_t)b * CC * (HH * WW);

    // ---- stage x rows h-1..h+1 as fp16, transposed+swizzled ----
    {
        // lane = (jj 0..15 -> col, cp 0..3 -> c-pair); wave wv covers 64 c.
        int jj = lane & 15, cp = lane >> 4;
        int j  = jj + 2;
        int swz = (j & 15) << 3;
        #pragma unroll
        for (int ci = 0; ci < 8; ++ci) {
            int c  = wv * 64 + ci * 8 + cp * 2;      // even
            int cs = c ^ swz;                        // bit0 preserved
            const float* xc0 = xb + (size_t)c * (HH * WW) + wq * 16 + jj;
            const float* xc1 = xc0 + HH * WW;
            #pragma unroll
            for (int r = 0; r < 3; ++r) {
                int y = h - 1 + r;
                float v0 = 0.f, v1 = 0.f;
                if (y >= 0 && y < HH) { v0 = xc0[y * WW]; v1 = xc1[y * WW]; }
                fp16x2 p = __builtin_amdgcn_cvt_pkrtz(v0, v1);
                *(fp16x2*)&xs[(r * SJ + j) * 128 + cs] = p;
            }
        }
        // halo cols j in {0,1,18,19} (xcol = 16wq + {-2,-1,16,17})
        for (int i = t; i < 3 * 4 * 128; i += 128) {
            int jh = i & 3;
            int c  = (i >> 2) & 127;
            int r  = i >> 9;
            int j2 = (jh < 2) ? jh : 16 + jh;
            int xcol = wq * 16 + j2 - 2;
            int y = h - 1 + r;
            float v = (xcol >= 0 && xcol < WW && y >= 0 && y < HH)
                    ? xb[(size_t)c * (HH * WW) + y * WW + xcol] : 0.f;
            xs[(r * SJ + j2) * 128 + (c ^ ((j2 & 15) << 3))] = (_Float16)v;
        }
    }
    __syncthreads();

    // ---- conv1 via MFMA fp16: D[kk][px] = sum_{c,dy,dx} w1*x ----
    int fpx = lane & 15, quad = lane >> 4;
    int mt = wv;
    floatx4 acc = {0.f, 0.f, 0.f, 0.f};
    #pragma unroll
    for (int dydx = 0; dydx < 9; ++dydx) {
        int r   = dydx / 3;
        int dxm = dydx - 3 * r;
        int j   = fpx + dxm + 1;                 // staged col, 1..18
        int rowbase = (r * SJ + j) * 128;
        int swz = (j & 15) << 3;
        const unsigned short* whb = w1f + (dydx * 2 + mt) * 2048 + lane * 8;
        #pragma unroll
        for (int ks = 0; ks < 4; ++ks) {
            int cb = (ks * 32 + quad * 8) ^ swz;
            half8 A = *(const half8*)(whb + ks * 512);
            half8 B = *(const half8*)&xs[rowbase + cb];
            acc = __builtin_amdgcn_mfma_f32_16x16x32_f16(A, B, acc, 0, 0, 0);
        }
    }
    #pragma unroll
    for (int reg = 0; reg < 4; ++reg) {          // D row = quad*4+reg
        int kk = mt * 16 + quad * 4 + reg;
        if (kk < KK) pk[kk * PXB + fpx] = acc[reg] + b1[kk];
    }
    __syncthreads();   // pk ready; xs dead -> sKT region reusable

    // ---- phase C: in-register softmax + pipelined attention ----
    // thread = (pp2 = t&7 -> px {2pp2, 2pp2+1}, cw = t>>3 -> 8 chunks of c)
    int pp2 = t & 7, cw = t >> 3;

    float2 lg[KK];
    #pragma unroll
    for (int k = 0; k < KK; ++k) lg[k] = *(const float2*)&pk[k * PXB + 2 * pp2];
    float m0 = -1e30f, m1 = -1e30f;
    #pragma unroll
    for (int k = 0; k < KK; ++k) { m0 = fmaxf(m0, lg[k].x); m1 = fmaxf(m1, lg[k].y); }
    float s0 = 0.f, s1 = 0.f;
    #pragma unroll
    for (int k = 0; k < KK; ++k) {
        lg[k].x = __expf(lg[k].x - m0); s0 += lg[k].x;
        lg[k].y = __expf(lg[k].y - m1); s1 += lg[k].y;
    }
    float i0 = 1.f / s0, i1 = 1.f / s1;
    #pragma unroll
    for (int k = 0; k < KK; ++k) { lg[k].x *= i0; lg[k].y *= i1; }

    int colg = wq * 16 + 2 * pp2 - 2;
    int coff[3]; float cmask[3];
    #pragma unroll
    for (int jx = 0; jx < 3; ++jx) {
        int cg = colg + 2 * jx;
        cmask[jx] = (cg >= 0 && cg <= WW - 2) ? 1.f : 0.f;
        coff[jx]  = min(max(cg, 0), WW - 2);
    }
    int yoff[5]; float msk[15];
    #pragma unroll
    for (int di = 0; di < 5; ++di) {
        int y = h + di - 2;
        float rm = (y >= 0 && y < HH) ? 1.f : 0.f;
        yoff[di] = min(max(y, 0), HH - 1) * WW;
        #pragma unroll
        for (int jx = 0; jx < 3; ++jx) msk[di * 3 + jx] = rm * cmask[jx];
    }

#define LOADC(BUF, I8) do {                                            \
    int c_ = (I8) * 16 + cw;                                           \
    const float* xc_ = xb + (size_t)c_ * (HH * WW);                    \
    _Pragma("unroll")                                                  \
    for (int di = 0; di < 5; ++di)                                     \
        _Pragma("unroll")                                              \
        for (int jx = 0; jx < 3; ++jx)                                 \
            BUF[di * 3 + jx] = *(const float2*)(xc_ + yoff[di] + coff[jx]); \
} while (0)

#define COMPST(BUF, I8) do {                                           \
    float t0 = 0.f, t1 = 0.f;                                          \
    _Pragma("unroll")                                                  \
    for (int di = 0; di < 5; ++di) {                                   \
        float2 x01 = BUF[di * 3 + 0];                                  \
        float2 x23 = BUF[di * 3 + 1];                                  \
        float2 x45 = BUF[di * 3 + 2];                                  \
        x01.x *= msk[di * 3 + 0]; x01.y *= msk[di * 3 + 0];            \
        x23.x *= msk[di * 3 + 1]; x23.y *= msk[di * 3 + 1];            \
        x45.x *= msk[di * 3 + 2]; x45.y *= msk[di * 3 + 2];            \
        t0 += lg[di*5+0].x * x01.x + lg[di*5+1].x * x01.y              \
            + lg[di*5+2].x * x23.x + lg[di*5+3].x * x23.y              \
            + lg[di*5+4].x * x45.x;                                    \
        t1 += lg[di*5+0].y * x01.y + lg[di*5+1].y * x23.x              \
            + lg[di*5+2].y * x23.y + lg[di*5+3].y * x45.x              \
            + lg[di*5+4].y * x45.y;                                    \
    }                                                                  \
    int cs_ = (I8) * 16 + cw;                                          \
    sKT[(2 * pp2) * 136 + cs_]     = f32_to_bf16(t0);                  \
    sKT[(2 * pp2 + 1) * 136 + cs_] = f32_to_bf16(t1);                  \
} while (0)

    {
        float2 bufA[15], bufB[15];
        LOADC(bufA, 0);
        for (int it = 0; it < 4; ++it) {
            LOADC(bufB, 2 * it + 1);         // prefetch odd chunk
            COMPST(bufA, 2 * it);
            if (it < 3) LOADC(bufA, 2 * it + 2);  // prefetch next even
            COMPST(bufB, 2 * it + 1);
        }
    }
    __syncthreads();

    // ---- MFMA2: C[o][px] = sum_c W2s[o][c] * s[c][px] ----
    // wave wv owns o-rows [64wv, 64wv+64): 4 o-tiles x 4 ks = 16 MFMA.
    floatx4 am[4] = {{0.f,0.f,0.f,0.f},{0.f,0.f,0.f,0.f},
                     {0.f,0.f,0.f,0.f},{0.f,0.f,0.f,0.f}};
    #pragma unroll
    for (int ks = 0; ks < 4; ++ks) {
        short8 bf = *(const short8*)&sKT[fpx * 136 + ks*32 + quad*8];
        #pragma unroll
        for (int mt2 = 0; mt2 < 4; ++mt2) {
            short8 af = *(const short8*)&w2o[(size_t)(64*wv + 16*mt2 + fpx) * CC
                                             + ks*32 + quad*8];
            am[mt2] = __builtin_amdgcn_mfma_f32_16x16x32_bf16(af, bf, am[mt2], 0, 0, 0);
        }
    }

    // ---- epilogue: D[row=quad*4+reg][col=fpx] + b2, 2x2-replicated write ----
    float* ob = out + (size_t)b * OUTC * (4 * HH * WW);
    int y0 = 2 * h;
    int pxo = wq * 16 + fpx;
    #pragma unroll
    for (int mt2 = 0; mt2 < 4; ++mt2) {
        #pragma unroll
        for (int reg = 0; reg < 4; ++reg) {
            int o = 64*wv + 16*mt2 + quad*4 + reg;
            float v = am[mt2][reg] + b2[o];
            float2 v2 = make_float2(v, v);
            float* r0p = ob + ((size_t)o * (2*HH) + y0) * (2*WW) + 2*pxo;
            *(float2*)(r0p)        = v2;
            *(float2*)(r0p + 2*WW) = v2;
        }
    }
}

// ---------------------------------------------------------------------------
extern "C" void kernel_launch(void* const* d_in, const int* in_sizes, int n_in,
                              void* d_out, int out_size, void* d_ws, size_t ws_size,
                              hipStream_t stream) {
    const float* x  = (const float*)d_in[0];
    const float* w1 = (const float*)d_in[1];
    const float* b1 = (const float*)d_in[2];
    const float* w2 = (const float*)d_in[3];
    const float* b2 = (const float*)d_in[4];
    float* out = (float*)d_out;

    unsigned short* w2o = (unsigned short*)d_ws;               // 32 KB
    unsigned short* w1f = w2o + (size_t)OUTC * CC;             // 72 KB

    prep_kernel<<<(16384 + 36864 + 255) / 256, 256, 0, stream>>>(w2, w1, w2o, w1f);
    fused_kernel<<<BB * HH * 4, 128, 0, stream>>>(x, w1f, w2o, b1, b2, out);
}